// Round 5
// baseline (622.215 us; speedup 1.0000x reference)
//
#include <hip/hip_runtime.h>

// 3-layer LSTM (T=1024,B=512,F=32,H1=32,H2=8,H3=8) + locked dropout.
//
// R15: remove the LDS self-round-trips from the recurrence chains.
// R14 post-mortem: every structural removal of a ~100-150cy item moved the
// wall only ~30cy -> the untouched items are the pacer: (1) wave0's
// h1 ds_write->ds_read turnaround, (2) wave1's sh23 turnaround, (3) wave1's
// h1ring read latency at top of step.
//  - wave0 dot: v_readlane of h1v (produced last iter, all lanes valid) ->
//    SGPR, consumed directly by v_fma_f32 (1 SGPR operand allowed). 32 RL +
//    64 FMA, zero LDS on the chain. h1ring write stays (off-chain, wave1).
//  - wave1 u-tail: 16 readlanes of hprev (lanes 0-7 h2, 32-39 h3) + 16 FMA;
//    sh23 buffer DELETED.
//  - wave1 h1-part: software-pipelined -- prefetch h1ring[i] (for step i+1)
//    into 8 float4 regs during step i; availability poll tgt = i+8.
// Kept: permlane32_swap builtin gates (R14), batched 4x ds_bpermute + one
// waitcnt (R12), barrier-free 3-wave producer/consumer (R11), bounded-spin
// LDS progress flags.

constexpr int T = 1024, B = 512, F = 32;
constexpr int H1 = 32, H2 = 8, H3 = 8;
constexpr int G1 = 4 * H1;          // 128 gate rows, layer 1
constexpr int HR = 128;             // h1 ring length (steps), 16KB
constexpr int XR = 64;              // xg ring length (steps), 32KB
constexpr int OUT_STRIDE = B * H3;  // 4096

typedef float f32x2 __attribute__((ext_vector_type(2)));
typedef unsigned int u32x2 __attribute__((ext_vector_type(2)));

#define PIN(v) asm volatile("" : "+v"(v))

#if __has_builtin(__builtin_amdgcn_rcpf)
#define RCPF(x) __builtin_amdgcn_rcpf(x)
#else
#define RCPF(x) (1.0f / (x))
#endif
#if __has_builtin(__builtin_amdgcn_exp2f)
#define EXP2F(x) __builtin_amdgcn_exp2f(x)
#else
#define EXP2F(x) exp2f(x)
#endif

#if __has_builtin(__builtin_amdgcn_permlane32_swap)
#define HAVE_PLSWAP 1
#else
#define HAVE_PLSWAP 0
#endif

// readlane: lane-uniform broadcast via VALU->SGPR (no LDS pipe)
#if __has_builtin(__builtin_amdgcn_readlane)
#define RLF(v, l) __uint_as_float(__builtin_amdgcn_readlane(__float_as_uint(v), (l)))
#else
#define RLF(v, l) __shfl((v), (l))
#endif

#define SIG_CM (-1.4426950408889634f)

__device__ __forceinline__ float act_f(float v, float cm, float ka, float kb) {
    return fmaf(ka, RCPF(1.0f + EXP2F(v * cm)), kb);
}
__device__ __forceinline__ float tanh_fast(float v) {
    return fmaf(2.0f, RCPF(1.0f + EXP2F(v * (2.0f * SIG_CM))), -1.0f);
}

// packed MAC: plain C vector math; -ffp-contract=fast -> v_pk_fma_f32
__device__ __forceinline__ void pkfma(f32x2& acc, f32x2 a, f32x2 b) {
    acc += a * b;
}

#define LDS_ACQ(p)    __hip_atomic_load((p), __ATOMIC_ACQUIRE, __HIP_MEMORY_SCOPE_WORKGROUP)
#define LDS_REL(p, v) __hip_atomic_store((p), (v), __ATOMIC_RELEASE, __HIP_MEMORY_SCOPE_WORKGROUP)
// bounded spin: correctness valve (cap ~0.5s); never reached when logic ok.
#define SPIN_UNTIL(EXPR)                                                       \
    do {                                                                       \
        int _g = 0;                                                            \
        while (!(EXPR)) {                                                      \
            __builtin_amdgcn_s_sleep(2);                                       \
            if (++_g > (1 << 22)) break;                                       \
        }                                                                      \
    } while (0)

__global__ __launch_bounds__(192, 1) void lstm3_fused_kernel(
    const float* __restrict__ x,
    const float* __restrict__ Wih1, const float* __restrict__ Whh1,
    const float* __restrict__ bih1, const float* __restrict__ bhh1,
    const float* __restrict__ Wih2, const float* __restrict__ Whh2,
    const float* __restrict__ bih2, const float* __restrict__ bhh2,
    const float* __restrict__ Wih3, const float* __restrict__ Whh3,
    const float* __restrict__ bih3, const float* __restrict__ bhh3,
    const float* __restrict__ mask1, const float* __restrict__ mask2,
    const float* __restrict__ mask3,
    float* __restrict__ out)
{
    const int tid = threadIdx.x;
    const int lane = tid & 63;
    const int wid = tid >> 6;
    const int b = blockIdx.x;

    __shared__ __align__(16) float h1ring[HR][H1];   // 16 KB
    __shared__ __align__(16) float xgring[XR][G1];   // 32 KB
    __shared__ __align__(16) float xstage[32][F];    //  4 KB (2 x 16-step tiles)
    __shared__ int prog0, prog1, prog2;

    if (tid == 0) { prog0 = 0; prog1 = 0; prog2 = 0; }
    if (wid == 0 && lane < H1) h1ring[HR - 1][lane] = 0.f;  // step -1 slot
    __syncthreads();  // the ONLY barrier in the kernel

    if (wid == 2) {
        // ================= wave 2: xg producer =================
        // rows lane and lane+64; xg[t][r] = dot(Wih1[r], x[t][b]) + bias[r]
        f32x2 wi0[16], wi1[16];
#pragma unroll
        for (int k = 0; k < 16; ++k) {
            wi0[k] = f32x2{Wih1[lane * F + 2 * k], Wih1[lane * F + 2 * k + 1]};
            wi1[k] = f32x2{Wih1[(lane + 64) * F + 2 * k], Wih1[(lane + 64) * F + 2 * k + 1]};
        }
        const float bias0 = bih1[lane] + bhh1[lane];
        const float bias1 = bih1[lane + 64] + bhh1[lane + 64];
#pragma unroll
        for (int k = 0; k < 16; ++k) { PIN(wi0[k]); PIN(wi1[k]); }

        const float4* x4 = (const float4*)x;  // x[t][b][f]: t-stride 4096 f4
        float4* xr4 = (float4*)xstage;
        const int ttq = lane >> 3, ffq = lane & 7;  // lane -> (step-in-tile, f4)

        // prologue: tile0 -> LDS (one exposed vmem latency), tile1 -> regs
        float4 sA = x4[(size_t)(0 + ttq) * 4096 + b * 8 + ffq];
        float4 sB = x4[(size_t)(8 + ttq) * 4096 + b * 8 + ffq];
        xr4[(ttq & 31) * 8 + ffq] = sA;
        xr4[((8 + ttq) & 31) * 8 + ffq] = sB;
        sA = x4[(size_t)(16 + ttq) * 4096 + b * 8 + ffq];
        sB = x4[(size_t)(24 + ttq) * 4096 + b * 8 + ffq];

        for (int t = 0; t < T; ++t) {
            if ((t & 15) == 0) {
                const int need = t - 40;  // xg ring backpressure vs wave0
                if (need > 0) SPIN_UNTIL(LDS_ACQ(&prog0) >= need);
                const int wt = t + 16;
                if (wt < T) {
                    xr4[((wt + ttq) & 31) * 8 + ffq] = sA;       // staged 16
                    xr4[((wt + 8 + ttq) & 31) * 8 + ffq] = sB;   // steps ago
                    const int lt = t + 32;
                    if (lt < T) {
                        sA = x4[(size_t)(lt + ttq) * 4096 + b * 8 + ffq];
                        sB = x4[(size_t)(lt + 8 + ttq) * 4096 + b * 8 + ffq];
                    }
                }
            }
            const float4* xp = (const float4*)xstage[t & 31];  // broadcast
            f32x2 aA = f32x2{bias0, 0.f}, aB = f32x2{0.f, 0.f};
            f32x2 cA = f32x2{bias1, 0.f}, cB = f32x2{0.f, 0.f};
#pragma unroll
            for (int q = 0; q < 8; ++q) {
                const float4 v = xp[q];
                const f32x2 lo = f32x2{v.x, v.y}, hi = f32x2{v.z, v.w};
                pkfma(aA, wi0[2 * q], lo); pkfma(aB, wi0[2 * q + 1], hi);
                pkfma(cA, wi1[2 * q], lo); pkfma(cB, wi1[2 * q + 1], hi);
            }
            const f32x2 sa = aA + aB, sc = cA + cB;
            xgring[t & (XR - 1)][lane] = sa.x + sa.y;    // 2-way bank, free
            xgring[t & (XR - 1)][lane + 64] = sc.x + sc.y;
            if ((t & 15) == 15) LDS_REL(&prog2, t + 1);
        }
    } else if (wid == 0) {
        // ================= wave 0: L1 recurrence =================
        // rows: r0=lane (0..63 = i|f over halves), r1=lane+64 (64..127 = g|o)
        // dot via readlane-broadcast of h1v (register-resident recurrence;
        // the h1ring WRITE remains, off the critical chain, for wave1).
        float w0[H1], w1[H1];
#pragma unroll
        for (int k = 0; k < H1; ++k) w0[k] = Whh1[lane * H1 + k];
#pragma unroll
        for (int k = 0; k < H1; ++k) w1[k] = Whh1[(lane + 64) * H1 + k];
#pragma unroll
        for (int k = 0; k < H1; ++k) { PIN(w0[k]); PIN(w1[k]); }
        // g0 rows are all sigmoid; g1: lanes<32 -> g-gate (tanh), else o (sig)
        const float cm1 = (lane < 32) ? 2.0f * SIG_CM : SIG_CM;
        const float ka1 = (lane < 32) ? 2.0f : 1.0f;
        const float kb1 = (lane < 32) ? -1.0f : 0.0f;
        float c1 = 0.f;
        float h1v = 0.f;  // h1(-1) = 0, register-resident

        SPIN_UNTIL(LDS_ACQ(&prog2) >= ((34 < T) ? 34 : T));
        float pa = xgring[0][lane], pb = xgring[0][lane + 64];
        float na = xgring[1][lane], nb = xgring[1][lane + 64];

        for (int i = 0; i < T; ++i) {
            if ((i & 31) == 0 && i) {  // xg availability, amortized /32
                int tgt = i + 34; if (tgt > T) tgt = T;
                SPIN_UNTIL(LDS_ACQ(&prog2) >= tgt);
            }
            if ((i & 63) == 0 && i >= 64)  // h1 ring backpressure vs wave1
                SPIN_UNTIL(LDS_ACQ(&prog1) >= i - 48);

            // 32 readlanes + 64 scalar FMA (8 indep chains), no LDS on chain
            float a0A = 0.f, a0B = 0.f, a0C = 0.f, a0D = 0.f;
            float a1A = 0.f, a1B = 0.f, a1C = 0.f, a1D = 0.f;
#pragma unroll
            for (int k = 0; k < 8; ++k) {
                const float s0 = RLF(h1v, k);
                const float s1 = RLF(h1v, k + 8);
                const float s2 = RLF(h1v, k + 16);
                const float s3 = RLF(h1v, k + 24);
                a0A = fmaf(s0, w0[k],      a0A);
                a0B = fmaf(s1, w0[k + 8],  a0B);
                a0C = fmaf(s2, w0[k + 16], a0C);
                a0D = fmaf(s3, w0[k + 24], a0D);
                a1A = fmaf(s0, w1[k],      a1A);
                a1B = fmaf(s1, w1[k + 8],  a1B);
                a1C = fmaf(s2, w1[k + 16], a1C);
                a1D = fmaf(s3, w1[k + 24], a1D);
            }
            const float a0 = pa + ((a0A + a0B) + (a0C + a0D));
            const float a1 = pb + ((a1A + a1B) + (a1C + a1D));
            const float g0 = act_f(a0, SIG_CM, 1.0f, 0.0f);  // [i|f]
            const float g1 = act_f(a1, cm1, ka1, kb1);       // [g|o]
            pa = na; pb = nb;
            {   // prefetch xg(i+2), clamped (slot guaranteed by poll window)
                int tn = i + 2; if (tn > T - 1) tn = T - 1;
                na = xgring[tn & (XR - 1)][lane];
                nb = xgring[tn & (XR - 1)][lane + 64];
            }
#if HAVE_PLSWAP
            // builtin returns {vdst_new, vsrc_new}; with both args = g0:
            // .x = [i|i], .y = [f|f]; for g1: .x = [g|g], .y = [o|o].
            const u32x2 pif = __builtin_amdgcn_permlane32_swap(
                __float_as_uint(g0), __float_as_uint(g0), false, false);
            const u32x2 pgo = __builtin_amdgcn_permlane32_swap(
                __float_as_uint(g1), __float_as_uint(g1), false, false);
            const float iv = __uint_as_float(pif.x);
            const float fv = __uint_as_float(pif.y);
            const float gv = __uint_as_float(pgo.x);
            const float ov = __uint_as_float(pgo.y);
            c1 = fmaf(fv, c1, iv * gv);                // c1 = f*c1 + i*g
            h1v = ov * tanh_fast(c1);                  // valid in ALL lanes
#else
            // fallback: lanes<32 get f=g0[j+32], o=g1[j+32]; high lanes junk
            // (readlane sources are k<32 only -> still correct).
            const float fv = __shfl_xor(g0, 32);
            const float ov = __shfl_xor(g1, 32);
            c1 = fmaf(fv, c1, g0 * g1);
            h1v = ov * tanh_fast(c1);
#endif
            if (lane < H1) h1ring[i & (HR - 1)][lane] = h1v;  // off-chain
            if ((i & 7) == 7) LDS_REL(&prog0, i + 1);
        }
    } else {
        // ========== wave 1: fused skewed L2(i-1)/L3(i-2) consumer ==========
        // h1-part: 16 pkfma over h1 prefetched ONE STEP AHEAD (8 float4 regs).
        // u-part: readlane of hprev (prev step's hnew; lanes 0-7 h2, 32-39 h3)
        // -> 16 scalar FMA. No sh23 buffer, no LDS self-turnaround.
        f32x2 wp[16];   // h1(32) weights as pairs (upper lanes: zeros)
        float wu[16];   // [h2(8) | h3(8)] weights
        float biasX, m3;
        const int r = lane & 31;
        const bool lower = (lane < 32);
        if (lower) {  // L2 gate row r (mask1 folded into Wih2)
#pragma unroll
            for (int k = 0; k < 16; ++k)
                wp[k] = f32x2{Wih2[r * H1 + 2 * k] * mask1[b * H1 + 2 * k],
                              Wih2[r * H1 + 2 * k + 1] * mask1[b * H1 + 2 * k + 1]};
#pragma unroll
            for (int k = 0; k < H2; ++k) wu[k] = Whh2[r * H2 + k];
#pragma unroll
            for (int k = 0; k < H3; ++k) wu[8 + k] = 0.0f;
            biasX = bih2[r] + bhh2[r];
        } else {      // L3 gate row r (mask2 folded into Wih3)
#pragma unroll
            for (int k = 0; k < 16; ++k) wp[k] = f32x2{0.f, 0.f};
#pragma unroll
            for (int k = 0; k < H2; ++k) wu[k] = Wih3[r * H2 + k] * mask2[b * H2 + k];
#pragma unroll
            for (int k = 0; k < H3; ++k) wu[8 + k] = Whh3[r * H3 + k];
            biasX = bih3[r] + bhh3[r];
        }
        const int sec = r >> 3;
        const float cmX = (sec == 2) ? 2.0f * SIG_CM : SIG_CM;
        const float kaX = (sec == 2) ? 2.0f : 1.0f;
        const float kbX = (sec == 2) ? -1.0f : 0.0f;
        m3 = mask3[b * H3 + (lane & 7)];
        const int thresh = lower ? 1 : 2;
        const int gbase = (lane & 32) + (lane & 7);
        // byte indices for the batched ds_bpermute gather (loop-invariant)
        const int bx0 = 4 * (gbase + 0),  bx1 = 4 * (gbase + 8);
        const int bx2 = 4 * (gbase + 16), bx3 = 4 * (gbase + 24);
#pragma unroll
        for (int k = 0; k < 16; ++k) { PIN(wp[k]); PIN(wu[k]); }

        float c23 = 0.f;
        float hprev = 0.f;  // prev fused step's hnew (h2/h3 state)
        // prefetch h1(-1) = zero slot
        const float4* hp0 = (const float4*)h1ring[HR - 1];
        float4 hq0 = hp0[0], hq1 = hp0[1], hq2 = hp0[2], hq3 = hp0[3];
        float4 hq4 = hp0[4], hq5 = hp0[5], hq6 = hp0[6], hq7 = hp0[7];

        for (int i = 0; i <= T + 1; ++i) {
            if ((i & 7) == 0) {  // h1 availability (+1 for the prefetch depth)
                int tgt = i + 8; if (tgt > T) tgt = T;
                SPIN_UNTIL(LDS_ACQ(&prog0) >= tgt);
            }
            // u-part via readlane of hprev (VALU only)
            float uA = 0.f, uB = 0.f;
#pragma unroll
            for (int k = 0; k < 8; ++k) {
                uA = fmaf(RLF(hprev, k),      wu[k],     uA);
                uB = fmaf(RLF(hprev, 32 + k), wu[8 + k], uB);
            }
            // h1-part from the prefetched registers (data is 1 step old)
            f32x2 s0 = f32x2{0.f, 0.f}, s1 = f32x2{0.f, 0.f};
            pkfma(s0, wp[0], f32x2{hq0.x, hq0.y}); pkfma(s0, wp[1], f32x2{hq0.z, hq0.w});
            pkfma(s0, wp[2], f32x2{hq1.x, hq1.y}); pkfma(s0, wp[3], f32x2{hq1.z, hq1.w});
            pkfma(s0, wp[4], f32x2{hq2.x, hq2.y}); pkfma(s0, wp[5], f32x2{hq2.z, hq2.w});
            pkfma(s0, wp[6], f32x2{hq3.x, hq3.y}); pkfma(s0, wp[7], f32x2{hq3.z, hq3.w});
            pkfma(s1, wp[8], f32x2{hq4.x, hq4.y}); pkfma(s1, wp[9], f32x2{hq4.z, hq4.w});
            pkfma(s1, wp[10], f32x2{hq5.x, hq5.y}); pkfma(s1, wp[11], f32x2{hq5.z, hq5.w});
            pkfma(s1, wp[12], f32x2{hq6.x, hq6.y}); pkfma(s1, wp[13], f32x2{hq6.z, hq6.w});
            pkfma(s1, wp[14], f32x2{hq7.x, hq7.y}); pkfma(s1, wp[15], f32x2{hq7.z, hq7.w});
            {   // prefetch h1(i) for step i+1 (stale/safe past the end)
                const float4* hp = (const float4*)h1ring[i & (HR - 1)];
                hq0 = hp[0]; hq1 = hp[1]; hq2 = hp[2]; hq3 = hp[3];
                hq4 = hp[4]; hq5 = hp[5]; hq6 = hp[6]; hq7 = hp[7];
            }
            const f32x2 sh = s0 + s1;
            const float a23 = biasX + (sh.x + sh.y) + (uA + uB);
            const float rv = act_f(a23, cmX, kaX, kbX);
            // batched gate gather: 4x ds_bpermute in flight, ONE waitcnt
            float gi, gf, gg, go;
            asm volatile(
                "ds_bpermute_b32 %0, %4, %8\n\t"
                "ds_bpermute_b32 %1, %5, %8\n\t"
                "ds_bpermute_b32 %2, %6, %8\n\t"
                "ds_bpermute_b32 %3, %7, %8\n\t"
                "s_waitcnt lgkmcnt(0)"
                : "=&v"(gi), "=&v"(gf), "=&v"(gg), "=&v"(go)
                : "v"(bx0), "v"(bx1), "v"(bx2), "v"(bx3), "v"(rv));
            c23 = (i >= thresh) ? fmaf(gf, c23, gi * gg) : 0.0f;
            const float hnew = go * tanh_fast(c23);  // h2(i-1) / h3(i-2)
            if (i >= 2 && (lane & 56) == 32)         // lanes 32-39: out(i-2)
                out[(size_t)(i - 2) * OUT_STRIDE + b * H3 + (lane & 7)] = hnew * m3;
            hprev = hnew;                            // register state handoff
            if ((i & 15) == 15) LDS_REL(&prog1, i + 1);
        }
    }
}

extern "C" void kernel_launch(void* const* d_in, const int* in_sizes, int n_in,
                              void* d_out, int out_size, void* d_ws, size_t ws_size,
                              hipStream_t stream) {
    (void)in_sizes; (void)n_in; (void)out_size; (void)d_ws; (void)ws_size;
    const float* x     = (const float*)d_in[0];
    const float* Wih1  = (const float*)d_in[1];
    const float* Whh1  = (const float*)d_in[2];
    const float* bih1  = (const float*)d_in[3];
    const float* bhh1  = (const float*)d_in[4];
    const float* Wih2  = (const float*)d_in[5];
    const float* Whh2  = (const float*)d_in[6];
    const float* bih2  = (const float*)d_in[7];
    const float* bhh2  = (const float*)d_in[8];
    const float* Wih3  = (const float*)d_in[9];
    const float* Whh3  = (const float*)d_in[10];
    const float* bih3  = (const float*)d_in[11];
    const float* bhh3  = (const float*)d_in[12];
    const float* mask1 = (const float*)d_in[13];
    const float* mask2 = (const float*)d_in[14];
    const float* mask3 = (const float*)d_in[15];
    float* out = (float*)d_out;

    lstm3_fused_kernel<<<dim3(B), dim3(192), 0, stream>>>(
        x, Wih1, Whh1, bih1, bhh1,
        Wih2, Whh2, bih2, bhh2,
        Wih3, Whh3, bih3, bhh3,
        mask1, mask2, mask3, out);
}

// Round 7
// 512.961 us; speedup vs baseline: 1.2130x; 1.2130x over previous
//
#include <hip/hip_runtime.h>

// 3-layer LSTM (T=1024,B=512,F=32,H1=32,H2=8,H3=8) + locked dropout.
//
// R17 = R16's verified math improvements + R14's PROVEN gate gather.
// R16 failed on ONE piece: DPP row_shr direction (rocPRIM scan idiom proves
// row_shr:N = lane i <- lane i-N, so consumer lanes got bound_ctrl ZEROS for
// f/o gates -> absmax 0.206). Exotic VALU gather shelved: EV ~9us vs 25%
// round-loss risk. This round banks the safe superset:
//  (a) cm-folding: activation scale constants folded into weights/biases at
//      init; every sigmoid = rcp(1+exp2(a_scaled)) with no pre-multiply;
//      c1/c23 kept in 2*SIG_CM-scaled domain (fold into g-gate ka/kb), so
//      tanh-path = exp2,add,rcp,fma(2o,.,-o). -2 trans-feeding muls per
//      step per chain. (verified algebraically line-by-line)
//  (b) dot accumulators seeded with pa/bias (kills final adds); 4 chains x
//      depth-4 pkfma everywhere.
//  (c) wave1 h1ring prefetched one step ahead into regs (poll tgt i+8
//      guarantees availability) -- removes ~120cy exposed read.
//  (d) wave1 gate gather: R14-proven 4x ds_bpermute + ONE waitcnt.
// Lessons standing: readlane broadcast loses to LDS turnaround (R15);
// permlane32_swap(a,a) = {.x=[lo|lo], .y=[hi|hi]} (R14-verified);
// inline-asm "+v" copies can be RA-coalesced into in-place ops (R12/R13).
// Structure (R11): barrier-free 3-wave producer/consumer; wave0 = L1
// recurrence, wave1 = fused skewed L2(i-1)/L3(i-2) + out, wave2 = xg
// producer. Bounded-spin LDS progress flags (no hang possible).

constexpr int T = 1024, B = 512, F = 32;
constexpr int H1 = 32, H2 = 8, H3 = 8;
constexpr int G1 = 4 * H1;          // 128 gate rows, layer 1
constexpr int HR = 128;             // h1 ring length (steps), 16KB
constexpr int XR = 64;              // xg ring length (steps), 32KB
constexpr int OUT_STRIDE = B * H3;  // 4096

typedef float f32x2 __attribute__((ext_vector_type(2)));
typedef unsigned int u32x2 __attribute__((ext_vector_type(2)));

#define PIN(v) asm volatile("" : "+v"(v))

#if __has_builtin(__builtin_amdgcn_rcpf)
#define RCPF(x) __builtin_amdgcn_rcpf(x)
#else
#define RCPF(x) (1.0f / (x))
#endif
#if __has_builtin(__builtin_amdgcn_exp2f)
#define EXP2F(x) __builtin_amdgcn_exp2f(x)
#else
#define EXP2F(x) exp2f(x)
#endif

#if __has_builtin(__builtin_amdgcn_permlane32_swap)
#define HAVE_PLSWAP 1
#else
#define HAVE_PLSWAP 0
#endif

#define SIG_CM (-1.4426950408889634f)   // -1/ln2

// packed MAC: plain C vector math; -ffp-contract=fast -> v_pk_fma_f32
__device__ __forceinline__ void pkfma(f32x2& acc, f32x2 a, f32x2 b) {
    acc += a * b;
}

#define LDS_ACQ(p)    __hip_atomic_load((p), __ATOMIC_ACQUIRE, __HIP_MEMORY_SCOPE_WORKGROUP)
#define LDS_REL(p, v) __hip_atomic_store((p), (v), __ATOMIC_RELEASE, __HIP_MEMORY_SCOPE_WORKGROUP)
// bounded spin: correctness valve (cap ~0.5s); never reached when logic ok.
#define SPIN_UNTIL(EXPR)                                                       \
    do {                                                                       \
        int _g = 0;                                                            \
        while (!(EXPR)) {                                                      \
            __builtin_amdgcn_s_sleep(2);                                       \
            if (++_g > (1 << 22)) break;                                       \
        }                                                                      \
    } while (0)

__global__ __launch_bounds__(192, 1) void lstm3_fused_kernel(
    const float* __restrict__ x,
    const float* __restrict__ Wih1, const float* __restrict__ Whh1,
    const float* __restrict__ bih1, const float* __restrict__ bhh1,
    const float* __restrict__ Wih2, const float* __restrict__ Whh2,
    const float* __restrict__ bih2, const float* __restrict__ bhh2,
    const float* __restrict__ Wih3, const float* __restrict__ Whh3,
    const float* __restrict__ bih3, const float* __restrict__ bhh3,
    const float* __restrict__ mask1, const float* __restrict__ mask2,
    const float* __restrict__ mask3,
    float* __restrict__ out)
{
    const int tid = threadIdx.x;
    const int lane = tid & 63;
    const int wid = tid >> 6;
    const int b = blockIdx.x;

    __shared__ __align__(16) float h1ring[HR][H1];   // 16 KB
    __shared__ __align__(16) float xgring[XR][G1];   // 32 KB (SCALED pre-acts)
    __shared__ __align__(16) float xstage[32][F];    //  4 KB (2 x 16-step tiles)
    __shared__ __align__(16) float sh23[2][16];      // wave1-private h2|h3
    __shared__ int prog0, prog1, prog2;

    if (tid == 0) { prog0 = 0; prog1 = 0; prog2 = 0; }
    if (wid == 0 && lane < H1) h1ring[HR - 1][lane] = 0.f;  // step -1 slot
    if (wid == 1 && lane < 16) { sh23[0][lane] = 0.f; sh23[1][lane] = 0.f; }
    __syncthreads();  // the ONLY barrier in the kernel

    if (wid == 2) {
        // ================= wave 2: xg producer (cm-scaled) =================
        // rows lane (i|f: cm=SIG_CM) and lane+64 (g: 2*SIG_CM, o: SIG_CM)
        const float cmA = SIG_CM;
        const float cmB = (lane < 32) ? 2.0f * SIG_CM : SIG_CM;
        f32x2 wi0[16], wi1[16];
#pragma unroll
        for (int k = 0; k < 16; ++k) {
            wi0[k] = f32x2{Wih1[lane * F + 2 * k] * cmA, Wih1[lane * F + 2 * k + 1] * cmA};
            wi1[k] = f32x2{Wih1[(lane + 64) * F + 2 * k] * cmB, Wih1[(lane + 64) * F + 2 * k + 1] * cmB};
        }
        const float bias0 = (bih1[lane] + bhh1[lane]) * cmA;
        const float bias1 = (bih1[lane + 64] + bhh1[lane + 64]) * cmB;
#pragma unroll
        for (int k = 0; k < 16; ++k) { PIN(wi0[k]); PIN(wi1[k]); }

        const float4* x4 = (const float4*)x;  // x[t][b][f]: t-stride 4096 f4
        float4* xr4 = (float4*)xstage;
        const int ttq = lane >> 3, ffq = lane & 7;  // lane -> (step-in-tile, f4)

        // prologue: tile0 -> LDS (one exposed vmem latency), tile1 -> regs
        float4 sA = x4[(size_t)(0 + ttq) * 4096 + b * 8 + ffq];
        float4 sB = x4[(size_t)(8 + ttq) * 4096 + b * 8 + ffq];
        xr4[(ttq & 31) * 8 + ffq] = sA;
        xr4[((8 + ttq) & 31) * 8 + ffq] = sB;
        sA = x4[(size_t)(16 + ttq) * 4096 + b * 8 + ffq];
        sB = x4[(size_t)(24 + ttq) * 4096 + b * 8 + ffq];

        for (int t = 0; t < T; ++t) {
            if ((t & 15) == 0) {
                const int need = t - 40;  // xg ring backpressure vs wave0
                if (need > 0) SPIN_UNTIL(LDS_ACQ(&prog0) >= need);
                const int wt = t + 16;
                if (wt < T) {
                    xr4[((wt + ttq) & 31) * 8 + ffq] = sA;       // staged 16
                    xr4[((wt + 8 + ttq) & 31) * 8 + ffq] = sB;   // steps ago
                    const int lt = t + 32;
                    if (lt < T) {
                        sA = x4[(size_t)(lt + ttq) * 4096 + b * 8 + ffq];
                        sB = x4[(size_t)(lt + 8 + ttq) * 4096 + b * 8 + ffq];
                    }
                }
            }
            const float4* xp = (const float4*)xstage[t & 31];  // broadcast
            f32x2 aA = f32x2{bias0, 0.f}, aB = f32x2{0.f, 0.f};
            f32x2 cA = f32x2{bias1, 0.f}, cB = f32x2{0.f, 0.f};
#pragma unroll
            for (int q = 0; q < 8; ++q) {
                const float4 v = xp[q];
                const f32x2 lo = f32x2{v.x, v.y}, hi = f32x2{v.z, v.w};
                pkfma(aA, wi0[2 * q], lo); pkfma(aB, wi0[2 * q + 1], hi);
                pkfma(cA, wi1[2 * q], lo); pkfma(cB, wi1[2 * q + 1], hi);
            }
            const f32x2 sa = aA + aB, sc = cA + cB;
            xgring[t & (XR - 1)][lane] = sa.x + sa.y;    // 2-way bank, free
            xgring[t & (XR - 1)][lane + 64] = sc.x + sc.y;
            if ((t & 15) == 15) LDS_REL(&prog2, t + 1);
        }
    } else if (wid == 0) {
        // ================= wave 0: L1 recurrence =================
        // rows: r0=lane (0..63 = i|f), r1=lane+64 (64..127 = g|o).
        // Weights pre-scaled by row cm; xg already scaled (wave2).
        const float s1d = 2.0f * SIG_CM;                      // c1 scale
        const float cm1 = (lane < 32) ? 2.0f * SIG_CM : SIG_CM;
        f32x2 w0[16], w1[16];
#pragma unroll
        for (int k = 0; k < 16; ++k) {
            w0[k] = f32x2{Whh1[lane * H1 + 2 * k] * SIG_CM, Whh1[lane * H1 + 2 * k + 1] * SIG_CM};
            w1[k] = f32x2{Whh1[(lane + 64) * H1 + 2 * k] * cm1, Whh1[(lane + 64) * H1 + 2 * k + 1] * cm1};
        }
#pragma unroll
        for (int k = 0; k < 16; ++k) { PIN(w0[k]); PIN(w1[k]); }
        // g1 act: g rows (lane<32) output g*s1d (fold into ka/kb); o rows plain
        const float ka1 = (lane < 32) ? (s1d + s1d) : 1.0f;
        const float kb1 = (lane < 32) ? -s1d : 0.0f;
        float c1s = 0.f;  // c1 * s1d

        SPIN_UNTIL(LDS_ACQ(&prog2) >= ((34 < T) ? 34 : T));
        float pa = xgring[0][lane], pb = xgring[0][lane + 64];
        float na = xgring[1][lane], nb = xgring[1][lane + 64];

        for (int i = 0; i < T; ++i) {
            if ((i & 31) == 0 && i) {  // xg availability, amortized /32
                int tgt = i + 34; if (tgt > T) tgt = T;
                SPIN_UNTIL(LDS_ACQ(&prog2) >= tgt);
            }
            if ((i & 63) == 0 && i >= 64)  // h1 ring backpressure vs wave1
                SPIN_UNTIL(LDS_ACQ(&prog1) >= i - 48);

            const float4* h1p = (const float4*)h1ring[(i - 1) & (HR - 1)];
            f32x2 hp2[16];
#pragma unroll
            for (int q = 0; q < 8; ++q) {
                const float4 v = h1p[q];
                hp2[2 * q] = f32x2{v.x, v.y};
                hp2[2 * q + 1] = f32x2{v.z, v.w};
            }
            // 4 chains x depth 4, accumulators init with pa/pb
            f32x2 A0 = f32x2{pa, 0.f}, A1 = f32x2{0.f, 0.f};
            f32x2 A2 = f32x2{0.f, 0.f}, A3 = f32x2{0.f, 0.f};
            f32x2 B0 = f32x2{pb, 0.f}, B1 = f32x2{0.f, 0.f};
            f32x2 B2 = f32x2{0.f, 0.f}, B3 = f32x2{0.f, 0.f};
#pragma unroll
            for (int d = 0; d < 4; ++d) {
                pkfma(A0, w0[0 + 4 * d], hp2[0 + 4 * d]);
                pkfma(A1, w0[1 + 4 * d], hp2[1 + 4 * d]);
                pkfma(A2, w0[2 + 4 * d], hp2[2 + 4 * d]);
                pkfma(A3, w0[3 + 4 * d], hp2[3 + 4 * d]);
                pkfma(B0, w1[0 + 4 * d], hp2[0 + 4 * d]);
                pkfma(B1, w1[1 + 4 * d], hp2[1 + 4 * d]);
                pkfma(B2, w1[2 + 4 * d], hp2[2 + 4 * d]);
                pkfma(B3, w1[3 + 4 * d], hp2[3 + 4 * d]);
            }
            const f32x2 SA = (A0 + A1) + (A2 + A3);
            const f32x2 SB = (B0 + B1) + (B2 + B3);
            const float a0s = SA.x + SA.y;   // already cm-scaled
            const float a1s = SB.x + SB.y;
            const float g0 = RCPF(1.0f + EXP2F(a0s));             // [i|f]
            const float g1 = fmaf(ka1, RCPF(1.0f + EXP2F(a1s)), kb1);  // [g*s|o]
            pa = na; pb = nb;
            {   // prefetch xg(i+2), clamped (slot guaranteed by poll window)
                int tn = i + 2; if (tn > T - 1) tn = T - 1;
                na = xgring[tn & (XR - 1)][lane];
                nb = xgring[tn & (XR - 1)][lane + 64];
            }
            float h1v;
#if HAVE_PLSWAP
            // swap(a,a): .x=[lo|lo], .y=[hi|hi] (verified R14)
            const u32x2 pif = __builtin_amdgcn_permlane32_swap(
                __float_as_uint(g0), __float_as_uint(g0), false, false);
            const u32x2 pgo = __builtin_amdgcn_permlane32_swap(
                __float_as_uint(g1), __float_as_uint(g1), false, false);
            const float iv = __uint_as_float(pif.x);   // [i|i]
            const float fv = __uint_as_float(pif.y);   // [f|f]
            const float gsv = __uint_as_float(pgo.x);  // [g*s|g*s]
            const float ov = __uint_as_float(pgo.y);   // [o|o]
            c1s = fmaf(fv, c1s, iv * gsv);             // c1s = f*c1s + i*g*s
            const float rt = RCPF(1.0f + EXP2F(c1s));  // tanh = 2*rt-1
            h1v = fmaf(ov + ov, rt, -ov);              // o*tanh(c1)
#else
            // fallback: lanes<32 get f=g0[j+32], o=g1[j+32]; high lanes junk
            const float fv = __shfl_xor(g0, 32);
            const float ov = __shfl_xor(g1, 32);
            c1s = fmaf(fv, c1s, g0 * g1);
            const float rt = RCPF(1.0f + EXP2F(c1s));
            h1v = fmaf(ov + ov, rt, -ov);
#endif
            if (lane < H1) h1ring[i & (HR - 1)][lane] = h1v;  // off-chain
            if ((i & 7) == 7) LDS_REL(&prog0, i + 1);
        }
    } else {
        // ========== wave 1: fused skewed L2(i-1)/L3(i-2) consumer ==========
        // 48-term dot over [h1(32) | h2(8) | h3(8)], weights cm-scaled.
        const float sX = 2.0f * SIG_CM;                 // c2/c3 scale
        const int r = lane & 31;
        const bool lower = (lane < 32);
        const int sec = r >> 3;
        const float cmX = (sec == 2) ? sX : SIG_CM;
        const float kaX = (sec == 2) ? (sX + sX) : 1.0f;
        const float kbX = (sec == 2) ? -sX : 0.0f;
        f32x2 wp[16];   // h1(32) weight pairs (cm-scaled; other layer: zeros)
        f32x2 wup[8];   // [h2(8) | h3(8)] weight pairs (cm-scaled)
        float biasX, m3;
        if (lower) {  // L2 gate row r (mask1 folded into Wih2)
#pragma unroll
            for (int k = 0; k < 16; ++k)
                wp[k] = f32x2{Wih2[r * H1 + 2 * k] * mask1[b * H1 + 2 * k] * cmX,
                              Wih2[r * H1 + 2 * k + 1] * mask1[b * H1 + 2 * k + 1] * cmX};
#pragma unroll
            for (int k = 0; k < 4; ++k)
                wup[k] = f32x2{Whh2[r * H2 + 2 * k] * cmX, Whh2[r * H2 + 2 * k + 1] * cmX};
#pragma unroll
            for (int k = 0; k < 4; ++k) wup[4 + k] = f32x2{0.f, 0.f};
            biasX = (bih2[r] + bhh2[r]) * cmX;
        } else {      // L3 gate row r (mask2 folded into Wih3)
#pragma unroll
            for (int k = 0; k < 16; ++k) wp[k] = f32x2{0.f, 0.f};
#pragma unroll
            for (int k = 0; k < 4; ++k)
                wup[k] = f32x2{Wih3[r * H2 + 2 * k] * mask2[b * H2 + 2 * k] * cmX,
                               Wih3[r * H2 + 2 * k + 1] * mask2[b * H2 + 2 * k + 1] * cmX};
#pragma unroll
            for (int k = 0; k < 4; ++k)
                wup[4 + k] = f32x2{Whh3[r * H3 + 2 * k] * cmX, Whh3[r * H3 + 2 * k + 1] * cmX};
            biasX = (bih3[r] + bhh3[r]) * cmX;
        }
        m3 = mask3[b * H3 + (lane & 7)];
        const int thresh = lower ? 1 : 2;
        const int gbase = (lane & 32) + (lane & 7);
        // byte indices for the batched ds_bpermute gather (loop-invariant)
        const int bx0 = 4 * (gbase + 0),  bx1 = 4 * (gbase + 8);
        const int bx2 = 4 * (gbase + 16), bx3 = 4 * (gbase + 24);
#pragma unroll
        for (int k = 0; k < 16; ++k) PIN(wp[k]);
#pragma unroll
        for (int k = 0; k < 8; ++k) PIN(wup[k]);

        float c23s = 0.f;  // c2/c3 * sX
        // prefetch h1(-1) = zero slot into regs (pairs)
        f32x2 hq2[16];
        {
            const float4* hp0 = (const float4*)h1ring[HR - 1];
#pragma unroll
            for (int q = 0; q < 8; ++q) {
                const float4 v = hp0[q];
                hq2[2 * q] = f32x2{v.x, v.y};
                hq2[2 * q + 1] = f32x2{v.z, v.w};
            }
        }

        for (int i = 0; i <= T + 1; ++i) {
            if ((i & 7) == 0) {  // h1 availability (+prefetch depth)
                int tgt = i + 8; if (tgt > T) tgt = T;
                SPIN_UNTIL(LDS_ACQ(&prog0) >= tgt);
            }
            const int par = i & 1;
            const float4* up = (const float4*)sh23[par ^ 1];
            const float4 u0 = up[0], u1 = up[1], u2 = up[2], u3 = up[3];
            // h1-part from prefetched regs: 4 chains x depth 4
            f32x2 S0 = f32x2{biasX, 0.f}, S1 = f32x2{0.f, 0.f};
            f32x2 S2 = f32x2{0.f, 0.f}, S3 = f32x2{0.f, 0.f};
#pragma unroll
            for (int d = 0; d < 4; ++d) {
                pkfma(S0, wp[0 + 4 * d], hq2[0 + 4 * d]);
                pkfma(S1, wp[1 + 4 * d], hq2[1 + 4 * d]);
                pkfma(S2, wp[2 + 4 * d], hq2[2 + 4 * d]);
                pkfma(S3, wp[3 + 4 * d], hq2[3 + 4 * d]);
            }
            {   // prefetch h1(i) for step i+1 (poll guarantees availability)
                const float4* hp = (const float4*)h1ring[i & (HR - 1)];
#pragma unroll
                for (int q = 0; q < 8; ++q) {
                    const float4 v = hp[q];
                    hq2[2 * q] = f32x2{v.x, v.y};
                    hq2[2 * q + 1] = f32x2{v.z, v.w};
                }
            }
            // u-part: 4 chains x depth 2
            f32x2 U0 = f32x2{0.f, 0.f}, U1 = f32x2{0.f, 0.f};
            f32x2 U2 = f32x2{0.f, 0.f}, U3 = f32x2{0.f, 0.f};
            pkfma(U0, wup[0], f32x2{u0.x, u0.y}); pkfma(U0, wup[4], f32x2{u2.x, u2.y});
            pkfma(U1, wup[1], f32x2{u0.z, u0.w}); pkfma(U1, wup[5], f32x2{u2.z, u2.w});
            pkfma(U2, wup[2], f32x2{u1.x, u1.y}); pkfma(U2, wup[6], f32x2{u3.x, u3.y});
            pkfma(U3, wup[3], f32x2{u1.z, u1.w}); pkfma(U3, wup[7], f32x2{u3.z, u3.w});
            const f32x2 ST = ((S0 + S1) + (S2 + S3)) + ((U0 + U1) + (U2 + U3));
            const float a23s = ST.x + ST.y;   // cm-scaled
            const float rv = fmaf(kaX, RCPF(1.0f + EXP2F(a23s)), kbX);
            // batched gate gather: 4x ds_bpermute in flight, ONE waitcnt
            // (R14-proven; deps flow through asm outputs)
            float gi, gf, gg, go;
            asm volatile(
                "ds_bpermute_b32 %0, %4, %8\n\t"
                "ds_bpermute_b32 %1, %5, %8\n\t"
                "ds_bpermute_b32 %2, %6, %8\n\t"
                "ds_bpermute_b32 %3, %7, %8\n\t"
                "s_waitcnt lgkmcnt(0)"
                : "=&v"(gi), "=&v"(gf), "=&v"(gg), "=&v"(go)
                : "v"(bx0), "v"(bx1), "v"(bx2), "v"(bx3), "v"(rv));
            c23s = (i >= thresh) ? fmaf(gf, c23s, gi * gg) : 0.0f;
            const float rt = RCPF(1.0f + EXP2F(c23s));   // tanh = 2*rt-1
            const float hnew = fmaf(go + go, rt, -go);   // h2(i-1) / h3(i-2)
            if (i >= 2 && (lane & 56) == 32)             // lanes 32-39: out(i-2)
                out[(size_t)(i - 2) * OUT_STRIDE + b * H3 + (lane & 7)] = hnew * m3;
            if ((lane & 24) == 0)                        // lanes 0-7 h2, 32-39 h3
                sh23[par][(lane & 7) | ((lane & 32) >> 2)] = hnew;
            if ((i & 15) == 15) LDS_REL(&prog1, i + 1);
        }
    }
}

extern "C" void kernel_launch(void* const* d_in, const int* in_sizes, int n_in,
                              void* d_out, int out_size, void* d_ws, size_t ws_size,
                              hipStream_t stream) {
    (void)in_sizes; (void)n_in; (void)out_size; (void)d_ws; (void)ws_size;
    const float* x     = (const float*)d_in[0];
    const float* Wih1  = (const float*)d_in[1];
    const float* Whh1  = (const float*)d_in[2];
    const float* bih1  = (const float*)d_in[3];
    const float* bhh1  = (const float*)d_in[4];
    const float* Wih2  = (const float*)d_in[5];
    const float* Whh2  = (const float*)d_in[6];
    const float* bih2  = (const float*)d_in[7];
    const float* bhh2  = (const float*)d_in[8];
    const float* Wih3  = (const float*)d_in[9];
    const float* Whh3  = (const float*)d_in[10];
    const float* bih3  = (const float*)d_in[11];
    const float* bhh3  = (const float*)d_in[12];
    const float* mask1 = (const float*)d_in[13];
    const float* mask2 = (const float*)d_in[14];
    const float* mask3 = (const float*)d_in[15];
    float* out = (float*)d_out;

    lstm3_fused_kernel<<<dim3(B), dim3(192), 0, stream>>>(
        x, Wih1, Whh1, bih1, bhh1,
        Wih2, Whh2, bih2, bhh2,
        Wih3, Whh3, bih3, bhh3,
        mask1, mask2, mask3, out);
}

// Round 8
// 507.617 us; speedup vs baseline: 1.2258x; 1.0105x over previous
//
#include <hip/hip_runtime.h>

// 3-layer LSTM (T=1024,B=512,F=32,H1=32,H2=8,H3=8) + locked dropout.
//
// R18 = R17 (443us) + in-order-LDS chain fix on wave1 + finer sleep.
// KEY INSIGHT: LDS ops complete IN ORDER within a wave. R14-R17 issued the
// 8x ds_read_b128 h1-prefetch BEFORE the bpermute asm whose s_waitcnt
// lgkmcnt(0) therefore had to drain the prefetch too -> prefetch latency
// was fully ON the serial gate chain every step. Fix: issue the prefetch
// AFTER the bpermute block ("memory" clobber pins the order); its latency
// now hides under c23/tanh/out-store/next-step U-dot.
// Also: s_sleep(2)->s_sleep(1) (halves wake quantization on stalls).
// This round is also a pacer diagnostic: it only shortens wave1's chain.
//
// Carried from R17: cm-folding (sigmoid = rcp(1+exp2(a_scaled)), c in
// 2*SIG_CM domain, tanh-path = exp2,add,rcp,fma), acc seeded with pa/bias,
// 4-chain x depth-4 pkfma dots, wave1 h1 prefetched 1 step ahead,
// permlane32_swap(a,a) = {.x=[lo|lo],.y=[hi|hi]} (R14-verified),
// batched 4x ds_bpermute + ONE waitcnt (R12-proven).
// Structure (R11): barrier-free 3-wave producer/consumer; wave0 = L1
// recurrence, wave1 = fused skewed L2(i-1)/L3(i-2) + out, wave2 = xg
// producer. Bounded-spin LDS progress flags (no hang possible).

constexpr int T = 1024, B = 512, F = 32;
constexpr int H1 = 32, H2 = 8, H3 = 8;
constexpr int G1 = 4 * H1;          // 128 gate rows, layer 1
constexpr int HR = 128;             // h1 ring length (steps), 16KB
constexpr int XR = 64;              // xg ring length (steps), 32KB
constexpr int OUT_STRIDE = B * H3;  // 4096

typedef float f32x2 __attribute__((ext_vector_type(2)));
typedef unsigned int u32x2 __attribute__((ext_vector_type(2)));

#define PIN(v) asm volatile("" : "+v"(v))

#if __has_builtin(__builtin_amdgcn_rcpf)
#define RCPF(x) __builtin_amdgcn_rcpf(x)
#else
#define RCPF(x) (1.0f / (x))
#endif
#if __has_builtin(__builtin_amdgcn_exp2f)
#define EXP2F(x) __builtin_amdgcn_exp2f(x)
#else
#define EXP2F(x) exp2f(x)
#endif

#if __has_builtin(__builtin_amdgcn_permlane32_swap)
#define HAVE_PLSWAP 1
#else
#define HAVE_PLSWAP 0
#endif

#define SIG_CM (-1.4426950408889634f)   // -1/ln2

// packed MAC: plain C vector math; -ffp-contract=fast -> v_pk_fma_f32
__device__ __forceinline__ void pkfma(f32x2& acc, f32x2 a, f32x2 b) {
    acc += a * b;
}

#define LDS_ACQ(p)    __hip_atomic_load((p), __ATOMIC_ACQUIRE, __HIP_MEMORY_SCOPE_WORKGROUP)
#define LDS_REL(p, v) __hip_atomic_store((p), (v), __ATOMIC_RELEASE, __HIP_MEMORY_SCOPE_WORKGROUP)
// bounded spin: correctness valve (cap ~0.5s); never reached when logic ok.
#define SPIN_UNTIL(EXPR)                                                       \
    do {                                                                       \
        int _g = 0;                                                            \
        while (!(EXPR)) {                                                      \
            __builtin_amdgcn_s_sleep(1);                                       \
            if (++_g > (1 << 23)) break;                                       \
        }                                                                      \
    } while (0)

__global__ __launch_bounds__(192, 1) void lstm3_fused_kernel(
    const float* __restrict__ x,
    const float* __restrict__ Wih1, const float* __restrict__ Whh1,
    const float* __restrict__ bih1, const float* __restrict__ bhh1,
    const float* __restrict__ Wih2, const float* __restrict__ Whh2,
    const float* __restrict__ bih2, const float* __restrict__ bhh2,
    const float* __restrict__ Wih3, const float* __restrict__ Whh3,
    const float* __restrict__ bih3, const float* __restrict__ bhh3,
    const float* __restrict__ mask1, const float* __restrict__ mask2,
    const float* __restrict__ mask3,
    float* __restrict__ out)
{
    const int tid = threadIdx.x;
    const int lane = tid & 63;
    const int wid = tid >> 6;
    const int b = blockIdx.x;

    __shared__ __align__(16) float h1ring[HR][H1];   // 16 KB
    __shared__ __align__(16) float xgring[XR][G1];   // 32 KB (SCALED pre-acts)
    __shared__ __align__(16) float xstage[32][F];    //  4 KB (2 x 16-step tiles)
    __shared__ __align__(16) float sh23[2][16];      // wave1-private h2|h3
    __shared__ int prog0, prog1, prog2;

    if (tid == 0) { prog0 = 0; prog1 = 0; prog2 = 0; }
    if (wid == 0 && lane < H1) h1ring[HR - 1][lane] = 0.f;  // step -1 slot
    if (wid == 1 && lane < 16) { sh23[0][lane] = 0.f; sh23[1][lane] = 0.f; }
    __syncthreads();  // the ONLY barrier in the kernel

    if (wid == 2) {
        // ================= wave 2: xg producer (cm-scaled) =================
        // rows lane (i|f: cm=SIG_CM) and lane+64 (g: 2*SIG_CM, o: SIG_CM)
        const float cmA = SIG_CM;
        const float cmB = (lane < 32) ? 2.0f * SIG_CM : SIG_CM;
        f32x2 wi0[16], wi1[16];
#pragma unroll
        for (int k = 0; k < 16; ++k) {
            wi0[k] = f32x2{Wih1[lane * F + 2 * k] * cmA, Wih1[lane * F + 2 * k + 1] * cmA};
            wi1[k] = f32x2{Wih1[(lane + 64) * F + 2 * k] * cmB, Wih1[(lane + 64) * F + 2 * k + 1] * cmB};
        }
        const float bias0 = (bih1[lane] + bhh1[lane]) * cmA;
        const float bias1 = (bih1[lane + 64] + bhh1[lane + 64]) * cmB;
#pragma unroll
        for (int k = 0; k < 16; ++k) { PIN(wi0[k]); PIN(wi1[k]); }

        const float4* x4 = (const float4*)x;  // x[t][b][f]: t-stride 4096 f4
        float4* xr4 = (float4*)xstage;
        const int ttq = lane >> 3, ffq = lane & 7;  // lane -> (step-in-tile, f4)

        // prologue: tile0 -> LDS (one exposed vmem latency), tile1 -> regs
        float4 sA = x4[(size_t)(0 + ttq) * 4096 + b * 8 + ffq];
        float4 sB = x4[(size_t)(8 + ttq) * 4096 + b * 8 + ffq];
        xr4[(ttq & 31) * 8 + ffq] = sA;
        xr4[((8 + ttq) & 31) * 8 + ffq] = sB;
        sA = x4[(size_t)(16 + ttq) * 4096 + b * 8 + ffq];
        sB = x4[(size_t)(24 + ttq) * 4096 + b * 8 + ffq];

        for (int t = 0; t < T; ++t) {
            if ((t & 15) == 0) {
                const int need = t - 40;  // xg ring backpressure vs wave0
                if (need > 0) SPIN_UNTIL(LDS_ACQ(&prog0) >= need);
                const int wt = t + 16;
                if (wt < T) {
                    xr4[((wt + ttq) & 31) * 8 + ffq] = sA;       // staged 16
                    xr4[((wt + 8 + ttq) & 31) * 8 + ffq] = sB;   // steps ago
                    const int lt = t + 32;
                    if (lt < T) {
                        sA = x4[(size_t)(lt + ttq) * 4096 + b * 8 + ffq];
                        sB = x4[(size_t)(lt + 8 + ttq) * 4096 + b * 8 + ffq];
                    }
                }
            }
            const float4* xp = (const float4*)xstage[t & 31];  // broadcast
            f32x2 aA = f32x2{bias0, 0.f}, aB = f32x2{0.f, 0.f};
            f32x2 cA = f32x2{bias1, 0.f}, cB = f32x2{0.f, 0.f};
#pragma unroll
            for (int q = 0; q < 8; ++q) {
                const float4 v = xp[q];
                const f32x2 lo = f32x2{v.x, v.y}, hi = f32x2{v.z, v.w};
                pkfma(aA, wi0[2 * q], lo); pkfma(aB, wi0[2 * q + 1], hi);
                pkfma(cA, wi1[2 * q], lo); pkfma(cB, wi1[2 * q + 1], hi);
            }
            const f32x2 sa = aA + aB, sc = cA + cB;
            xgring[t & (XR - 1)][lane] = sa.x + sa.y;    // 2-way bank, free
            xgring[t & (XR - 1)][lane + 64] = sc.x + sc.y;
            if ((t & 15) == 15) LDS_REL(&prog2, t + 1);
        }
    } else if (wid == 0) {
        // ================= wave 0: L1 recurrence =================
        // rows: r0=lane (0..63 = i|f), r1=lane+64 (64..127 = g|o).
        // Weights pre-scaled by row cm; xg already scaled (wave2).
        const float s1d = 2.0f * SIG_CM;                      // c1 scale
        const float cm1 = (lane < 32) ? 2.0f * SIG_CM : SIG_CM;
        f32x2 w0[16], w1[16];
#pragma unroll
        for (int k = 0; k < 16; ++k) {
            w0[k] = f32x2{Whh1[lane * H1 + 2 * k] * SIG_CM, Whh1[lane * H1 + 2 * k + 1] * SIG_CM};
            w1[k] = f32x2{Whh1[(lane + 64) * H1 + 2 * k] * cm1, Whh1[(lane + 64) * H1 + 2 * k + 1] * cm1};
        }
#pragma unroll
        for (int k = 0; k < 16; ++k) { PIN(w0[k]); PIN(w1[k]); }
        // g1 act: g rows (lane<32) output g*s1d (fold into ka/kb); o rows plain
        const float ka1 = (lane < 32) ? (s1d + s1d) : 1.0f;
        const float kb1 = (lane < 32) ? -s1d : 0.0f;
        float c1s = 0.f;  // c1 * s1d

        SPIN_UNTIL(LDS_ACQ(&prog2) >= ((34 < T) ? 34 : T));
        float pa = xgring[0][lane], pb = xgring[0][lane + 64];
        float na = xgring[1][lane], nb = xgring[1][lane + 64];

        for (int i = 0; i < T; ++i) {
            if ((i & 31) == 0 && i) {  // xg availability, amortized /32
                int tgt = i + 34; if (tgt > T) tgt = T;
                SPIN_UNTIL(LDS_ACQ(&prog2) >= tgt);
            }
            if ((i & 63) == 0 && i >= 64)  // h1 ring backpressure vs wave1
                SPIN_UNTIL(LDS_ACQ(&prog1) >= i - 48);

            const float4* h1p = (const float4*)h1ring[(i - 1) & (HR - 1)];
            f32x2 hp2[16];
#pragma unroll
            for (int q = 0; q < 8; ++q) {
                const float4 v = h1p[q];
                hp2[2 * q] = f32x2{v.x, v.y};
                hp2[2 * q + 1] = f32x2{v.z, v.w};
            }
            // 4 chains x depth 4, accumulators init with pa/pb
            f32x2 A0 = f32x2{pa, 0.f}, A1 = f32x2{0.f, 0.f};
            f32x2 A2 = f32x2{0.f, 0.f}, A3 = f32x2{0.f, 0.f};
            f32x2 B0 = f32x2{pb, 0.f}, B1 = f32x2{0.f, 0.f};
            f32x2 B2 = f32x2{0.f, 0.f}, B3 = f32x2{0.f, 0.f};
#pragma unroll
            for (int d = 0; d < 4; ++d) {
                pkfma(A0, w0[0 + 4 * d], hp2[0 + 4 * d]);
                pkfma(A1, w0[1 + 4 * d], hp2[1 + 4 * d]);
                pkfma(A2, w0[2 + 4 * d], hp2[2 + 4 * d]);
                pkfma(A3, w0[3 + 4 * d], hp2[3 + 4 * d]);
                pkfma(B0, w1[0 + 4 * d], hp2[0 + 4 * d]);
                pkfma(B1, w1[1 + 4 * d], hp2[1 + 4 * d]);
                pkfma(B2, w1[2 + 4 * d], hp2[2 + 4 * d]);
                pkfma(B3, w1[3 + 4 * d], hp2[3 + 4 * d]);
            }
            const f32x2 SA = (A0 + A1) + (A2 + A3);
            const f32x2 SB = (B0 + B1) + (B2 + B3);
            const float a0s = SA.x + SA.y;   // already cm-scaled
            const float a1s = SB.x + SB.y;
            const float g0 = RCPF(1.0f + EXP2F(a0s));             // [i|f]
            const float g1 = fmaf(ka1, RCPF(1.0f + EXP2F(a1s)), kb1);  // [g*s|o]
            pa = na; pb = nb;
            {   // prefetch xg(i+2), clamped (slot guaranteed by poll window)
                int tn = i + 2; if (tn > T - 1) tn = T - 1;
                na = xgring[tn & (XR - 1)][lane];
                nb = xgring[tn & (XR - 1)][lane + 64];
            }
            float h1v;
#if HAVE_PLSWAP
            // swap(a,a): .x=[lo|lo], .y=[hi|hi] (verified R14)
            const u32x2 pif = __builtin_amdgcn_permlane32_swap(
                __float_as_uint(g0), __float_as_uint(g0), false, false);
            const u32x2 pgo = __builtin_amdgcn_permlane32_swap(
                __float_as_uint(g1), __float_as_uint(g1), false, false);
            const float iv = __uint_as_float(pif.x);   // [i|i]
            const float fv = __uint_as_float(pif.y);   // [f|f]
            const float gsv = __uint_as_float(pgo.x);  // [g*s|g*s]
            const float ov = __uint_as_float(pgo.y);   // [o|o]
            c1s = fmaf(fv, c1s, iv * gsv);             // c1s = f*c1s + i*g*s
            const float rt = RCPF(1.0f + EXP2F(c1s));  // tanh = 2*rt-1
            h1v = fmaf(ov + ov, rt, -ov);              // o*tanh(c1)
#else
            // fallback: lanes<32 get f=g0[j+32], o=g1[j+32]; high lanes junk
            const float fv = __shfl_xor(g0, 32);
            const float ov = __shfl_xor(g1, 32);
            c1s = fmaf(fv, c1s, g0 * g1);
            const float rt = RCPF(1.0f + EXP2F(c1s));
            h1v = fmaf(ov + ov, rt, -ov);
#endif
            if (lane < H1) h1ring[i & (HR - 1)][lane] = h1v;  // off-chain
            if ((i & 7) == 7) LDS_REL(&prog0, i + 1);
        }
    } else {
        // ========== wave 1: fused skewed L2(i-1)/L3(i-2) consumer ==========
        // 48-term dot over [h1(32) | h2(8) | h3(8)], weights cm-scaled.
        const float sX = 2.0f * SIG_CM;                 // c2/c3 scale
        const int r = lane & 31;
        const bool lower = (lane < 32);
        const int sec = r >> 3;
        const float cmX = (sec == 2) ? sX : SIG_CM;
        const float kaX = (sec == 2) ? (sX + sX) : 1.0f;
        const float kbX = (sec == 2) ? -sX : 0.0f;
        f32x2 wp[16];   // h1(32) weight pairs (cm-scaled; other layer: zeros)
        f32x2 wup[8];   // [h2(8) | h3(8)] weight pairs (cm-scaled)
        float biasX, m3;
        if (lower) {  // L2 gate row r (mask1 folded into Wih2)
#pragma unroll
            for (int k = 0; k < 16; ++k)
                wp[k] = f32x2{Wih2[r * H1 + 2 * k] * mask1[b * H1 + 2 * k] * cmX,
                              Wih2[r * H1 + 2 * k + 1] * mask1[b * H1 + 2 * k + 1] * cmX};
#pragma unroll
            for (int k = 0; k < 4; ++k)
                wup[k] = f32x2{Whh2[r * H2 + 2 * k] * cmX, Whh2[r * H2 + 2 * k + 1] * cmX};
#pragma unroll
            for (int k = 0; k < 4; ++k) wup[4 + k] = f32x2{0.f, 0.f};
            biasX = (bih2[r] + bhh2[r]) * cmX;
        } else {      // L3 gate row r (mask2 folded into Wih3)
#pragma unroll
            for (int k = 0; k < 16; ++k) wp[k] = f32x2{0.f, 0.f};
#pragma unroll
            for (int k = 0; k < 4; ++k)
                wup[k] = f32x2{Wih3[r * H2 + 2 * k] * mask2[b * H2 + 2 * k] * cmX,
                               Wih3[r * H2 + 2 * k + 1] * mask2[b * H2 + 2 * k + 1] * cmX};
#pragma unroll
            for (int k = 0; k < 4; ++k)
                wup[4 + k] = f32x2{Whh3[r * H3 + 2 * k] * cmX, Whh3[r * H3 + 2 * k + 1] * cmX};
            biasX = (bih3[r] + bhh3[r]) * cmX;
        }
        m3 = mask3[b * H3 + (lane & 7)];
        const int thresh = lower ? 1 : 2;
        const int gbase = (lane & 32) + (lane & 7);
        // byte indices for the batched ds_bpermute gather (loop-invariant)
        const int bx0 = 4 * (gbase + 0),  bx1 = 4 * (gbase + 8);
        const int bx2 = 4 * (gbase + 16), bx3 = 4 * (gbase + 24);
#pragma unroll
        for (int k = 0; k < 16; ++k) PIN(wp[k]);
#pragma unroll
        for (int k = 0; k < 8; ++k) PIN(wup[k]);

        float c23s = 0.f;  // c2/c3 * sX
        // prefetch h1(-1) = zero slot into regs (pairs)
        f32x2 hq2[16];
        {
            const float4* hp0 = (const float4*)h1ring[HR - 1];
#pragma unroll
            for (int q = 0; q < 8; ++q) {
                const float4 v = hp0[q];
                hq2[2 * q] = f32x2{v.x, v.y};
                hq2[2 * q + 1] = f32x2{v.z, v.w};
            }
        }

        for (int i = 0; i <= T + 1; ++i) {
            if ((i & 7) == 0) {  // h1 availability (+prefetch depth)
                int tgt = i + 8; if (tgt > T) tgt = T;
                SPIN_UNTIL(LDS_ACQ(&prog0) >= tgt);
            }
            const int par = i & 1;
            const float4* up = (const float4*)sh23[par ^ 1];
            const float4 u0 = up[0], u1 = up[1], u2 = up[2], u3 = up[3];
            // h1-part from prefetched regs: 4 chains x depth 4
            f32x2 S0 = f32x2{biasX, 0.f}, S1 = f32x2{0.f, 0.f};
            f32x2 S2 = f32x2{0.f, 0.f}, S3 = f32x2{0.f, 0.f};
#pragma unroll
            for (int d = 0; d < 4; ++d) {
                pkfma(S0, wp[0 + 4 * d], hq2[0 + 4 * d]);
                pkfma(S1, wp[1 + 4 * d], hq2[1 + 4 * d]);
                pkfma(S2, wp[2 + 4 * d], hq2[2 + 4 * d]);
                pkfma(S3, wp[3 + 4 * d], hq2[3 + 4 * d]);
            }
            // u-part: 4 chains x depth 2
            f32x2 U0 = f32x2{0.f, 0.f}, U1 = f32x2{0.f, 0.f};
            f32x2 U2 = f32x2{0.f, 0.f}, U3 = f32x2{0.f, 0.f};
            pkfma(U0, wup[0], f32x2{u0.x, u0.y}); pkfma(U0, wup[4], f32x2{u2.x, u2.y});
            pkfma(U1, wup[1], f32x2{u0.z, u0.w}); pkfma(U1, wup[5], f32x2{u2.z, u2.w});
            pkfma(U2, wup[2], f32x2{u1.x, u1.y}); pkfma(U2, wup[6], f32x2{u3.x, u3.y});
            pkfma(U3, wup[3], f32x2{u1.z, u1.w}); pkfma(U3, wup[7], f32x2{u3.z, u3.w});
            const f32x2 ST = ((S0 + S1) + (S2 + S3)) + ((U0 + U1) + (U2 + U3));
            const float a23s = ST.x + ST.y;   // cm-scaled
            const float rv = fmaf(kaX, RCPF(1.0f + EXP2F(a23s)), kbX);
            // batched gate gather: 4x ds_bpermute in flight, ONE waitcnt.
            // "memory" clobber pins program order: the h1 prefetch below MUST
            // stay AFTER this block (LDS completes in-order; any ds_read
            // issued before it would be drained by the lgkmcnt(0) -> its
            // latency lands on the serial chain, the R14-R17 hidden cost).
            float gi, gf, gg, go;
            asm volatile(
                "ds_bpermute_b32 %0, %4, %8\n\t"
                "ds_bpermute_b32 %1, %5, %8\n\t"
                "ds_bpermute_b32 %2, %6, %8\n\t"
                "ds_bpermute_b32 %3, %7, %8\n\t"
                "s_waitcnt lgkmcnt(0)"
                : "=&v"(gi), "=&v"(gf), "=&v"(gg), "=&v"(go)
                : "v"(bx0), "v"(bx1), "v"(bx2), "v"(bx3), "v"(rv)
                : "memory");
            {   // prefetch h1(i) for step i+1 -- issued AFTER the gather;
                // latency hides under c23/tanh/out/next U-dot.
                const float4* hp = (const float4*)h1ring[i & (HR - 1)];
#pragma unroll
                for (int q = 0; q < 8; ++q) {
                    const float4 v = hp[q];
                    hq2[2 * q] = f32x2{v.x, v.y};
                    hq2[2 * q + 1] = f32x2{v.z, v.w};
                }
            }
            c23s = (i >= thresh) ? fmaf(gf, c23s, gi * gg) : 0.0f;
            const float rt = RCPF(1.0f + EXP2F(c23s));   // tanh = 2*rt-1
            const float hnew = fmaf(go + go, rt, -go);   // h2(i-1) / h3(i-2)
            if (i >= 2 && (lane & 56) == 32)             // lanes 32-39: out(i-2)
                out[(size_t)(i - 2) * OUT_STRIDE + b * H3 + (lane & 7)] = hnew * m3;
            if ((lane & 24) == 0)                        // lanes 0-7 h2, 32-39 h3
                sh23[par][(lane & 7) | ((lane & 32) >> 2)] = hnew;
            if ((i & 15) == 15) LDS_REL(&prog1, i + 1);
        }
    }
}

extern "C" void kernel_launch(void* const* d_in, const int* in_sizes, int n_in,
                              void* d_out, int out_size, void* d_ws, size_t ws_size,
                              hipStream_t stream) {
    (void)in_sizes; (void)n_in; (void)out_size; (void)d_ws; (void)ws_size;
    const float* x     = (const float*)d_in[0];
    const float* Wih1  = (const float*)d_in[1];
    const float* Whh1  = (const float*)d_in[2];
    const float* bih1  = (const float*)d_in[3];
    const float* bhh1  = (const float*)d_in[4];
    const float* Wih2  = (const float*)d_in[5];
    const float* Whh2  = (const float*)d_in[6];
    const float* bih2  = (const float*)d_in[7];
    const float* bhh2  = (const float*)d_in[8];
    const float* Wih3  = (const float*)d_in[9];
    const float* Whh3  = (const float*)d_in[10];
    const float* bih3  = (const float*)d_in[11];
    const float* bhh3  = (const float*)d_in[12];
    const float* mask1 = (const float*)d_in[13];
    const float* mask2 = (const float*)d_in[14];
    const float* mask3 = (const float*)d_in[15];
    float* out = (float*)d_out;

    lstm3_fused_kernel<<<dim3(B), dim3(192), 0, stream>>>(
        x, Wih1, Whh1, bih1, bhh1,
        Wih2, Whh2, bih2, bhh2,
        Wih3, Whh3, bih3, bhh3,
        mask1, mask2, mask3, out);
}